// Round 13
// baseline (91.907 us; speedup 1.0000x reference)
//
#include <hip/hip_runtime.h>

// Decoder: 2-layer LSTM (H=32) + MLP (96), B=16384, 25 steps.
// R13 = R8 generalized to 4 streams/wave, 4-wave m-split, ET=64, grid=256
// (1 block/CU, 1 wave/SIMD). Model: time = issue x latency-inflation;
// inflation 2.8x at 2 chains/SIMD (R6 TLP == R8 ILP), predict ~2.0x at 4.
// Per-wave issue unchanged vs R8 (2x streams, 1/2 m-tiles). BARRIER_NOVM
// (R12: vmcnt drain irrelevant). exp2-prescale (R7+). f32 I/O (R2-proved).

#define PRED 25
#define BATCH 16384
#define ET    64    // 4 streams x 16
#define XROW  192   // xh row (u16): 0..95 x/curr, 96..127 h0_A, 128..159 h0_B
#define HROW  128   // hh row: 0..31 h0, 32..63 h1_A, 64..95 h1_B
#define LROW  64    // h1lo row

typedef unsigned short u16;
typedef unsigned int   u32;
typedef __attribute__((ext_vector_type(8))) short bf16x8;
typedef __attribute__((ext_vector_type(4))) float f32x4;

#define LOG2E  1.44269504088896340736f
#define LOG2E2 2.88539008177792681472f

#define BARRIER_NOVM() asm volatile("s_waitcnt lgkmcnt(0)\ns_barrier" ::: "memory")

__device__ __forceinline__ float rcp_(float x){ return __builtin_amdgcn_rcpf(x); }
__device__ __forceinline__ float ex2(float x){ return __builtin_amdgcn_exp2f(x); }
__device__ __forceinline__ float sigm2(float xp){ return rcp_(1.0f + ex2(-xp)); }
__device__ __forceinline__ float tanh2(float xp){ return 1.0f - 2.0f*rcp_(ex2(xp) + 1.0f); }

__device__ __forceinline__ u16 f2b(float f){
  u32 i = __float_as_uint(f);
  i += 0x7FFFu + ((i >> 16) & 1u);
  return (u16)(i >> 16);
}
__device__ __forceinline__ float b2f(u16 u){ return __uint_as_float(((u32)u) << 16); }

struct __align__(16) SM {
  u16 xh[4][16*XROW];
  u16 hh[4][16*HROW];
  u16 h1lo[4][16*LROW];
};

__device__ __forceinline__ int swx(int e, int k){ return e*XROW + (k ^ ((e&7)<<3)); }
__device__ __forceinline__ int swh(int e, int k){ return e*HROW + (k ^ ((e&7)<<3)); }
__device__ __forceinline__ int swl(int e, int k){ return e*LROW + (k ^ ((e&7)<<3)); }

__device__ __forceinline__ bf16x8 pack8s(const float* src, float s){
  union { bf16x8 v; u16 h[8]; } fr;
  #pragma unroll
  for (int j = 0; j < 8; ++j) fr.h[j] = f2b(src[j]*s);
  return fr.v;
}

extern "C" __global__ __launch_bounds__(256, 1)
void decoder_kernel(const float* __restrict__ obs,  const float* __restrict__ lat,
                    const float* __restrict__ Wfc,  const float* __restrict__ bfc,
                    const float* __restrict__ Wih0, const float* __restrict__ Whh0,
                    const float* __restrict__ bih0, const float* __restrict__ bhh0,
                    const float* __restrict__ Wih1, const float* __restrict__ Whh1,
                    const float* __restrict__ bih1, const float* __restrict__ bhh1,
                    const float* __restrict__ Wmlp, const float* __restrict__ bmlp,
                    float* __restrict__ out)
{
  __shared__ SM sm;
  const int tid = threadIdx.x;
  const int ebase = blockIdx.x * ET;
  const int mh = tid >> 6;        // wave 0..3 = m-quarter
  const int l  = tid & 63;
  const int lr = l & 15;          // row/col in 16-tile; e within stream
  const int kq = l >> 4;          // k-quad 0..3
  const bool nt2 = (mh < 2);      // waves 0,1 own a second MLP tile

  // ---- one-time LDS init: x = obs[15] (bf16), h_init -> h0/h1 parity 0 ----
  {
    int e = tid >> 2, c0 = (tid & 3)*24;
    int s = e >> 4, er = e & 15;
    const float* src = obs + ((size_t)(15*BATCH) + ebase + e)*96 + c0;
    #pragma unroll
    for (int j = 0; j < 12; ++j){
      float2 v = *(const float2*)(src + 2*j);
      u32 pk = (u32)f2b(v.x) | ((u32)f2b(v.y) << 16);
      *(u32*)&sm.xh[s][swx(er, c0 + 2*j)] = pk;
    }
  }
  {
    int u = tid & 31, e8 = (tid >> 5)*8;
    const float* wf = Wfc + u*16;
    float bb = bfc[u];
    #pragma unroll
    for (int r = 0; r < 8; ++r){
      int e = e8 + r, s = e >> 4, er = e & 15;
      const float* lp = lat + (size_t)(ebase + e)*16;
      float a = bb;
      #pragma unroll
      for (int j = 0; j < 16; ++j) a = fmaf(wf[j], lp[j], a);
      u16 hb = f2b(a);
      sm.xh[s][swx(er, 96 + u)] = hb;   // h0 parity 0
      sm.hh[s][swh(er, 32 + u)] = hb;   // h1 parity 0
    }
  }

  // ---- preload weight A-fragments (2 m-tiles/wave; gate rows pre-scaled) ----
  bf16x8 aw0[2][4];                 // GEMM0: 2 m-tiles x 4 k-chunks
  #pragma unroll
  for (int i = 0; i < 2; ++i){
    int vg = (mh*2 + i)*16 + lr;
    int g  = (vg & 3)*32 + (vg >> 2);     // gate-permuted row
    float sc = ((vg & 3) == 2) ? LOG2E2 : LOG2E;
    #pragma unroll
    for (int c = 0; c < 4; ++c){
      int k = c*32 + kq*8;
      const float* src = (k < 96) ? (Wih0 + g*96 + k) : (Whh0 + g*32 + (k - 96));
      aw0[i][c] = pack8s(src, sc);
    }
  }
  bf16x8 aw1[2][2];                 // GEMM1: K=64
  #pragma unroll
  for (int i = 0; i < 2; ++i){
    int vg = (mh*2 + i)*16 + lr;
    int g  = (vg & 3)*32 + (vg >> 2);
    float sc = ((vg & 3) == 2) ? LOG2E2 : LOG2E;
    #pragma unroll
    for (int c = 0; c < 2; ++c){
      int k = c*32 + kq*8;
      const float* src = (k < 32) ? (Wih1 + g*32 + k) : (Whh1 + g*32 + (k - 32));
      aw1[i][c] = pack8s(src, sc);
    }
  }
  // MLP: 6 m-tiles over 4 waves: wave mh owns {mh} and {mh+4 if mh<2}
  bf16x8 awm[2];
  f32x4 biasmv[2];
  #pragma unroll
  for (int it = 0; it < 2; ++it){
    int tm = mh + it*4;
    if (it == 0 || nt2){
      int o = tm*16 + lr;
      awm[it] = pack8s(Wmlp + o*32 + kq*8, 1.0f);
      int o0 = tm*16 + kq*4;
      #pragma unroll
      for (int r = 0; r < 4; ++r) biasmv[it][r] = bmlp[o0 + r];
    }
  }

  // ---- gate biases (C-frag rows = kq*4 + r; scaled like their gate rows) ----
  f32x4 bias0v[2], bias1v[2];
  #pragma unroll
  for (int i = 0; i < 2; ++i){
    int u = (mh*2 + i)*4 + kq;
    #pragma unroll
    for (int r = 0; r < 4; ++r){
      int g = r*32 + u;
      float sc = (r == 2) ? LOG2E2 : LOG2E;
      bias0v[i][r] = (bih0[g] + bhh0[g])*sc;
      bias1v[i][r] = (bih1[g] + bhh1[g])*sc;
    }
  }

  float c0s[4][2] = {{0,0},{0,0},{0,0},{0,0}};
  float c1s[4][2] = {{0,0},{0,0},{0,0},{0,0}};

  __syncthreads();   // init visible (one-time)

  f32x4 am[4][2];    // MLP results, stored to global AFTER B5

  for (int t = 0; t < PRED; ++t){
    const int p = t & 1;
    // ---- P1: GEMM0, 4 independent streams ----
    f32x4 g0[4][2];
    #pragma unroll
    for (int s = 0; s < 4; ++s){
      bf16x8 bx0 = *(const bf16x8*)&sm.xh[s][swx(lr, 0*32 + kq*8)];
      bf16x8 bx1 = *(const bf16x8*)&sm.xh[s][swx(lr, 1*32 + kq*8)];
      bf16x8 bx2 = *(const bf16x8*)&sm.xh[s][swx(lr, 2*32 + kq*8)];
      bf16x8 bx3 = *(const bf16x8*)&sm.xh[s][swx(lr, 96 + 32*p + kq*8)];
      #pragma unroll
      for (int i = 0; i < 2; ++i){
        f32x4 a = bias0v[i];
        a = __builtin_amdgcn_mfma_f32_16x16x32_bf16(aw0[i][0], bx0, a, 0, 0, 0);
        a = __builtin_amdgcn_mfma_f32_16x16x32_bf16(aw0[i][1], bx1, a, 0, 0, 0);
        a = __builtin_amdgcn_mfma_f32_16x16x32_bf16(aw0[i][2], bx2, a, 0, 0, 0);
        a = __builtin_amdgcn_mfma_f32_16x16x32_bf16(aw0[i][3], bx3, a, 0, 0, 0);
        g0[s][i] = a;
      }
    }
    // ---- LSTM0 activation; h0 -> xh parity p^1 + hh rows 0..31 ----
    #pragma unroll
    for (int s = 0; s < 4; ++s)
      #pragma unroll
      for (int i = 0; i < 2; ++i){
        float ig = sigm2(g0[s][i][0]);
        float fg = sigm2(g0[s][i][1]);
        float gg = tanh2(g0[s][i][2]);
        float og = sigm2(g0[s][i][3]);
        float cn = fmaf(fg, c0s[s][i], ig*gg);
        c0s[s][i] = cn;
        u16 hb = f2b(og * tanh2(cn*LOG2E2));
        int u = (mh*2 + i)*4 + kq;
        sm.xh[s][swx(lr, 96 + 32*(p^1) + u)] = hb;
        sm.hh[s][swh(lr, u)] = hb;
      }
    BARRIER_NOVM();   // B2: h0 visible
    // ---- P3: GEMM1, 4 streams ----
    f32x4 g1[4][2];
    #pragma unroll
    for (int s = 0; s < 4; ++s){
      bf16x8 bh0 = *(const bf16x8*)&sm.hh[s][swh(lr, kq*8)];
      bf16x8 bh1 = *(const bf16x8*)&sm.hh[s][swh(lr, 32 + 32*p + kq*8)];
      #pragma unroll
      for (int i = 0; i < 2; ++i){
        f32x4 a = bias1v[i];
        a = __builtin_amdgcn_mfma_f32_16x16x32_bf16(aw1[i][0], bh0, a, 0, 0, 0);
        a = __builtin_amdgcn_mfma_f32_16x16x32_bf16(aw1[i][1], bh1, a, 0, 0, 0);
        g1[s][i] = a;
      }
    }
    #pragma unroll
    for (int s = 0; s < 4; ++s)
      #pragma unroll
      for (int i = 0; i < 2; ++i){
        float ig = sigm2(g1[s][i][0]);
        float fg = sigm2(g1[s][i][1]);
        float gg = tanh2(g1[s][i][2]);
        float og = sigm2(g1[s][i][3]);
        float cn = fmaf(fg, c1s[s][i], ig*gg);
        c1s[s][i] = cn;
        float h1 = og * tanh2(cn*LOG2E2);
        u16 hi = f2b(h1);
        u16 lo = f2b(h1 - b2f(hi));
        int u = (mh*2 + i)*4 + kq;
        sm.hh[s][swh(lr, 32 + 32*(p^1) + u)] = hi;   // h1_new
        sm.h1lo[s][swl(lr, u)] = lo;                 // residual for MLP split
      }
    BARRIER_NOVM();   // B4: h1 visible
    // ---- P4: MLP, 4 streams; bf16 feedback to xh; f32 deferred ----
    #pragma unroll
    for (int s = 0; s < 4; ++s){
      bf16x8 bmh = *(const bf16x8*)&sm.hh[s][swh(lr, 32 + 32*(p^1) + kq*8)];
      bf16x8 bml = *(const bf16x8*)&sm.h1lo[s][swl(lr, kq*8)];
      #pragma unroll
      for (int it = 0; it < 2; ++it){
        if (it == 0 || nt2){
          int tm = mh + it*4;
          f32x4 a = biasmv[it];
          a = __builtin_amdgcn_mfma_f32_16x16x32_bf16(awm[it], bmh, a, 0, 0, 0);
          a = __builtin_amdgcn_mfma_f32_16x16x32_bf16(awm[it], bml, a, 0, 0, 0);
          am[s][it] = a;
          int o0 = tm*16 + kq*4;
          u32 pk01 = (u32)f2b(a[0]) | ((u32)f2b(a[1]) << 16);
          u32 pk23 = (u32)f2b(a[2]) | ((u32)f2b(a[3]) << 16);
          *(u32*)&sm.xh[s][swx(lr, o0)]     = pk01;   // next step's x
          *(u32*)&sm.xh[s][swx(lr, o0 + 2)] = pk23;
        }
      }
    }
    BARRIER_NOVM();   // B5: next x visible for P1(t+1)
    // ---- global stores AFTER barrier: never drained in-loop ----
    #pragma unroll
    for (int s = 0; s < 4; ++s){
      float* outb = out + (size_t)t*BATCH*96 + (size_t)(ebase + s*16 + lr)*96;
      #pragma unroll
      for (int it = 0; it < 2; ++it){
        if (it == 0 || nt2){
          int tm = mh + it*4;
          *(f32x4*)(outb + tm*16 + kq*4) = am[s][it];
        }
      }
    }
  }
}

extern "C" void kernel_launch(void* const* d_in, const int* in_sizes, int n_in,
                              void* d_out, int out_size, void* d_ws, size_t ws_size,
                              hipStream_t stream){
  decoder_kernel<<<dim3(BATCH/ET), dim3(256), 0, stream>>>(
      (const float*)d_in[0],  (const float*)d_in[1],
      (const float*)d_in[3],  (const float*)d_in[4],
      (const float*)d_in[5],  (const float*)d_in[6],
      (const float*)d_in[7],  (const float*)d_in[8],
      (const float*)d_in[9],  (const float*)d_in[10],
      (const float*)d_in[11], (const float*)d_in[12],
      (const float*)d_in[13], (const float*)d_in[14],
      (float*)d_out);
}

// Round 14
// 76.822 us; speedup vs baseline: 1.1964x; 1.1964x over previous
//
#include <hip/hip_runtime.h>

// Decoder: 2-layer LSTM (H=32) + MLP (96), B=16384, 25 steps.
// R14 = R12 (= best R8 + lgkm-only barriers) with ONE change: all hot-loop
// bf16 conversions use native __bf16 casts (hardware v_cvt_pk_bf16_f32, RNE)
// instead of 5-op bit-twiddle f2b. Cuts ~25% of per-step VALU issue
// (~280 -> ~30 ops/wave/step on conversions). Everything else identical.

#define PRED 25
#define BATCH 16384
#define ET    32    // 2 streams x 16
#define XROW  192   // xh row (u16): 0..95 x/curr, 96..127 h0_A, 128..159 h0_B
#define HROW  128   // hh row: 0..31 h0, 32..63 h1_A, 64..95 h1_B
#define LROW  64    // h1lo row

typedef unsigned short u16;
typedef unsigned int   u32;
typedef __attribute__((ext_vector_type(8))) short bf16x8;
typedef __attribute__((ext_vector_type(4))) float f32x4;

#define LOG2E  1.44269504088896340736f
#define LOG2E2 2.88539008177792681472f

#define BARRIER_NOVM() asm volatile("s_waitcnt lgkmcnt(0)\ns_barrier" ::: "memory")

__device__ __forceinline__ float rcp_(float x){ return __builtin_amdgcn_rcpf(x); }
__device__ __forceinline__ float ex2(float x){ return __builtin_amdgcn_exp2f(x); }
__device__ __forceinline__ float sigm2(float xp){ return rcp_(1.0f + ex2(-xp)); }
__device__ __forceinline__ float tanh2(float xp){ return 1.0f - 2.0f*rcp_(ex2(xp) + 1.0f); }

// native bf16 convert (hardware v_cvt_pk_bf16_f32, RNE) — m240: use scalar
// casts, compiler fuses pairs; do NOT hand-write the asm.
__device__ __forceinline__ u16 f2b(float f){
  __bf16 b = (__bf16)f;
  return __builtin_bit_cast(u16, b);
}
__device__ __forceinline__ u32 f2b2(float lo, float hi){
  return (u32)f2b(lo) | ((u32)f2b(hi) << 16);
}
__device__ __forceinline__ float b2f(u16 u){ return __uint_as_float(((u32)u) << 16); }

struct __align__(16) SM {
  u16 xh[2][16*XROW];
  u16 hh[2][16*HROW];
  u16 h1lo[2][16*LROW];
};

__device__ __forceinline__ int swx(int e, int k){ return e*XROW + (k ^ ((e&7)<<3)); }
__device__ __forceinline__ int swh(int e, int k){ return e*HROW + (k ^ ((e&7)<<3)); }
__device__ __forceinline__ int swl(int e, int k){ return e*LROW + (k ^ ((e&7)<<3)); }

__device__ __forceinline__ bf16x8 pack8s(const float* src, float s){
  union { bf16x8 v; u16 h[8]; } fr;
  #pragma unroll
  for (int j = 0; j < 8; ++j) fr.h[j] = f2b(src[j]*s);
  return fr.v;
}

extern "C" __global__ __launch_bounds__(128, 1)
void decoder_kernel(const float* __restrict__ obs,  const float* __restrict__ lat,
                    const float* __restrict__ Wfc,  const float* __restrict__ bfc,
                    const float* __restrict__ Wih0, const float* __restrict__ Whh0,
                    const float* __restrict__ bih0, const float* __restrict__ bhh0,
                    const float* __restrict__ Wih1, const float* __restrict__ Whh1,
                    const float* __restrict__ bih1, const float* __restrict__ bhh1,
                    const float* __restrict__ Wmlp, const float* __restrict__ bmlp,
                    float* __restrict__ out)
{
  __shared__ SM sm;
  const int tid = threadIdx.x;
  const int ebase = blockIdx.x * ET;
  const int mh = tid >> 6;        // wave 0..1 = m-half
  const int l  = tid & 63;
  const int lr = l & 15;          // row/col in 16-tile; e within stream
  const int kq = l >> 4;          // k-quad 0..3

  // ---- one-time LDS init: x = obs[15] (bf16), h_init -> h0/h1 parity 0 ----
  {
    int e = tid >> 2, c0 = (tid & 3)*24;
    int s = e >> 4, er = e & 15;
    const float* src = obs + ((size_t)(15*BATCH) + ebase + e)*96 + c0;
    #pragma unroll
    for (int j = 0; j < 12; ++j){
      float2 v = *(const float2*)(src + 2*j);
      *(u32*)&sm.xh[s][swx(er, c0 + 2*j)] = f2b2(v.x, v.y);
    }
  }
  {
    int u = tid & 31, e8 = (tid >> 5)*8;
    const float* wf = Wfc + u*16;
    float bb = bfc[u];
    #pragma unroll
    for (int r = 0; r < 8; ++r){
      int e = e8 + r, s = e >> 4, er = e & 15;
      const float* lp = lat + (size_t)(ebase + e)*16;
      float a = bb;
      #pragma unroll
      for (int j = 0; j < 16; ++j) a = fmaf(wf[j], lp[j], a);
      u16 hb = f2b(a);
      sm.xh[s][swx(er, 96 + u)] = hb;   // h0 parity 0
      sm.hh[s][swh(er, 32 + u)] = hb;   // h1 parity 0
    }
  }

  // ---- preload weight A-fragments (step-invariant; gate rows pre-scaled) ----
  bf16x8 aw0[4][4];                 // GEMM0: 4 m-tiles x 4 k-chunks
  #pragma unroll
  for (int i = 0; i < 4; ++i){
    int vg = (mh*4 + i)*16 + lr;
    int g  = (vg & 3)*32 + (vg >> 2);     // gate-permuted row
    float sc = ((vg & 3) == 2) ? LOG2E2 : LOG2E;
    #pragma unroll
    for (int c = 0; c < 4; ++c){
      int k = c*32 + kq*8;
      const float* src = (k < 96) ? (Wih0 + g*96 + k) : (Whh0 + g*32 + (k - 96));
      aw0[i][c] = pack8s(src, sc);
    }
  }
  bf16x8 aw1[4][2];                 // GEMM1: K=64
  #pragma unroll
  for (int i = 0; i < 4; ++i){
    int vg = (mh*4 + i)*16 + lr;
    int g  = (vg & 3)*32 + (vg >> 2);
    float sc = ((vg & 3) == 2) ? LOG2E2 : LOG2E;
    #pragma unroll
    for (int c = 0; c < 2; ++c){
      int k = c*32 + kq*8;
      const float* src = (k < 32) ? (Wih1 + g*32 + k) : (Whh1 + g*32 + (k - 32));
      aw1[i][c] = pack8s(src, sc);
    }
  }
  bf16x8 awm[3];                    // MLP: 3 m-tiles per wave, K=32
  #pragma unroll
  for (int i = 0; i < 3; ++i){
    int o = (mh*3 + i)*16 + lr;
    awm[i] = pack8s(Wmlp + o*32 + kq*8, 1.0f);
  }

  // ---- biases (C-frag rows = kq*4 + r; scaled like their gate rows) ----
  f32x4 bias0v[4], bias1v[4];
  #pragma unroll
  for (int i = 0; i < 4; ++i){
    int u = (mh*4 + i)*4 + kq;
    #pragma unroll
    for (int r = 0; r < 4; ++r){
      int g = r*32 + u;
      float sc = (r == 2) ? LOG2E2 : LOG2E;
      bias0v[i][r] = (bih0[g] + bhh0[g])*sc;
      bias1v[i][r] = (bih1[g] + bhh1[g])*sc;
    }
  }
  f32x4 biasmv[3];
  #pragma unroll
  for (int i = 0; i < 3; ++i){
    int o0 = (mh*3 + i)*16 + kq*4;
    #pragma unroll
    for (int r = 0; r < 4; ++r) biasmv[i][r] = bmlp[o0 + r];
  }

  float c0s[2][4] = {{0,0,0,0},{0,0,0,0}};
  float c1s[2][4] = {{0,0,0,0},{0,0,0,0}};

  __syncthreads();   // init visible (one-time; full drain harmless here)

  f32x4 am[2][3];    // MLP results, stored to global AFTER B5

  for (int t = 0; t < PRED; ++t){
    const int p = t & 1;
    // ---- P1: GEMM0 both streams (independent -> ILP) ----
    f32x4 g0[2][4];
    #pragma unroll
    for (int s = 0; s < 2; ++s){
      bf16x8 bx0 = *(const bf16x8*)&sm.xh[s][swx(lr, 0*32 + kq*8)];
      bf16x8 bx1 = *(const bf16x8*)&sm.xh[s][swx(lr, 1*32 + kq*8)];
      bf16x8 bx2 = *(const bf16x8*)&sm.xh[s][swx(lr, 2*32 + kq*8)];
      bf16x8 bx3 = *(const bf16x8*)&sm.xh[s][swx(lr, 96 + 32*p + kq*8)];
      #pragma unroll
      for (int i = 0; i < 4; ++i){
        f32x4 a = bias0v[i];
        a = __builtin_amdgcn_mfma_f32_16x16x32_bf16(aw0[i][0], bx0, a, 0, 0, 0);
        a = __builtin_amdgcn_mfma_f32_16x16x32_bf16(aw0[i][1], bx1, a, 0, 0, 0);
        a = __builtin_amdgcn_mfma_f32_16x16x32_bf16(aw0[i][2], bx2, a, 0, 0, 0);
        a = __builtin_amdgcn_mfma_f32_16x16x32_bf16(aw0[i][3], bx3, a, 0, 0, 0);
        g0[s][i] = a;
      }
    }
    // ---- LSTM0 activation; h0 -> xh parity p^1 + hh rows 0..31 ----
    #pragma unroll
    for (int s = 0; s < 2; ++s)
      #pragma unroll
      for (int i = 0; i < 4; ++i){
        float ig = sigm2(g0[s][i][0]);
        float fg = sigm2(g0[s][i][1]);
        float gg = tanh2(g0[s][i][2]);
        float og = sigm2(g0[s][i][3]);
        float cn = fmaf(fg, c0s[s][i], ig*gg);
        c0s[s][i] = cn;
        u16 hb = f2b(og * tanh2(cn*LOG2E2));
        int u = (mh*4 + i)*4 + kq;
        sm.xh[s][swx(lr, 96 + 32*(p^1) + u)] = hb;
        sm.hh[s][swh(lr, u)] = hb;
      }
    BARRIER_NOVM();   // B2: h0 visible; stores stay in flight
    // ---- P3: GEMM1 both streams ----
    f32x4 g1[2][4];
    #pragma unroll
    for (int s = 0; s < 2; ++s){
      bf16x8 bh0 = *(const bf16x8*)&sm.hh[s][swh(lr, kq*8)];
      bf16x8 bh1 = *(const bf16x8*)&sm.hh[s][swh(lr, 32 + 32*p + kq*8)];
      #pragma unroll
      for (int i = 0; i < 4; ++i){
        f32x4 a = bias1v[i];
        a = __builtin_amdgcn_mfma_f32_16x16x32_bf16(aw1[i][0], bh0, a, 0, 0, 0);
        a = __builtin_amdgcn_mfma_f32_16x16x32_bf16(aw1[i][1], bh1, a, 0, 0, 0);
        g1[s][i] = a;
      }
    }
    #pragma unroll
    for (int s = 0; s < 2; ++s)
      #pragma unroll
      for (int i = 0; i < 4; ++i){
        float ig = sigm2(g1[s][i][0]);
        float fg = sigm2(g1[s][i][1]);
        float gg = tanh2(g1[s][i][2]);
        float og = sigm2(g1[s][i][3]);
        float cn = fmaf(fg, c1s[s][i], ig*gg);
        c1s[s][i] = cn;
        float h1 = og * tanh2(cn*LOG2E2);
        u16 hi = f2b(h1);
        u16 lo = f2b(h1 - b2f(hi));
        int u = (mh*4 + i)*4 + kq;
        sm.hh[s][swh(lr, 32 + 32*(p^1) + u)] = hi;   // h1_new
        sm.h1lo[s][swl(lr, u)] = lo;                 // residual for MLP split
      }
    BARRIER_NOVM();   // B4: h1 visible
    // ---- P4: MLP both streams; bf16 feedback to xh; f32 result deferred ----
    #pragma unroll
    for (int s = 0; s < 2; ++s){
      bf16x8 bmh = *(const bf16x8*)&sm.hh[s][swh(lr, 32 + 32*(p^1) + kq*8)];
      bf16x8 bml = *(const bf16x8*)&sm.h1lo[s][swl(lr, kq*8)];
      #pragma unroll
      for (int i = 0; i < 3; ++i){
        f32x4 a = biasmv[i];
        a = __builtin_amdgcn_mfma_f32_16x16x32_bf16(awm[i], bmh, a, 0, 0, 0);
        a = __builtin_amdgcn_mfma_f32_16x16x32_bf16(awm[i], bml, a, 0, 0, 0);
        am[s][i] = a;
        int o0 = (mh*3 + i)*16 + kq*4;
        *(u32*)&sm.xh[s][swx(lr, o0)]     = f2b2(a[0], a[1]);   // next step's x
        *(u32*)&sm.xh[s][swx(lr, o0 + 2)] = f2b2(a[2], a[3]);
      }
    }
    BARRIER_NOVM();   // B5: next x visible for P1(t+1)
    // ---- global stores AFTER barrier: never drained in-loop ----
    #pragma unroll
    for (int s = 0; s < 2; ++s){
      float* outb = out + (size_t)t*BATCH*96 + (size_t)(ebase + s*16 + lr)*96;
      #pragma unroll
      for (int i = 0; i < 3; ++i){
        int o0 = (mh*3 + i)*16 + kq*4;
        *(f32x4*)(outb + o0) = am[s][i];
      }
    }
  }
}

extern "C" void kernel_launch(void* const* d_in, const int* in_sizes, int n_in,
                              void* d_out, int out_size, void* d_ws, size_t ws_size,
                              hipStream_t stream){
  decoder_kernel<<<dim3(BATCH/ET), dim3(128), 0, stream>>>(
      (const float*)d_in[0],  (const float*)d_in[1],
      (const float*)d_in[3],  (const float*)d_in[4],
      (const float*)d_in[5],  (const float*)d_in[6],
      (const float*)d_in[7],  (const float*)d_in[8],
      (const float*)d_in[9],  (const float*)d_in[10],
      (const float*)d_in[11], (const float*)d_in[12],
      (const float*)d_in[13], (const float*)d_in[14],
      (float*)d_out);
}

// Round 15
// 72.354 us; speedup vs baseline: 1.2702x; 1.0617x over previous
//
#include <hip/hip_runtime.h>

// Decoder: 2-layer LSTM (H=32) + MLP (96), B=16384, 25 steps.
// R15 = R14 with redundant work stripped:
//  - h1 hi/lo split DROPPED (lo fed only the MLP; bf16-h1 adds ~6.5e-4 to
//    output, budget 4.24e-3). P4: 3 MFMAs (was 6), P3: no lo pack/writes.
//  - h0 deduplicated: single parity-buffered region in hh (GEMM0 reads
//    parity p, GEMM1 reads p^1). 8 fewer ds_writes/step.
//  - xh holds only x (96 cols, XROW=128; XOR swizzle bijective per row).
// Everything else identical to R14 (2-wave m-split, 2 streams, lgkm-only
// barriers, exp2-prescale, native bf16 cvt, f32 I/O).

#define PRED 25
#define BATCH 16384
#define ET    32    // 2 streams x 16
#define XROW  128   // xh row (u16): 0..95 x/curr (+pad to 128 for swizzle)
#define HROW  128   // hh row: 0..31 h0_A, 32..63 h0_B, 64..95 h1_A, 96..127 h1_B

typedef unsigned short u16;
typedef unsigned int   u32;
typedef __attribute__((ext_vector_type(8))) short bf16x8;
typedef __attribute__((ext_vector_type(4))) float f32x4;

#define LOG2E  1.44269504088896340736f
#define LOG2E2 2.88539008177792681472f

#define BARRIER_NOVM() asm volatile("s_waitcnt lgkmcnt(0)\ns_barrier" ::: "memory")

__device__ __forceinline__ float rcp_(float x){ return __builtin_amdgcn_rcpf(x); }
__device__ __forceinline__ float ex2(float x){ return __builtin_amdgcn_exp2f(x); }
__device__ __forceinline__ float sigm2(float xp){ return rcp_(1.0f + ex2(-xp)); }
__device__ __forceinline__ float tanh2(float xp){ return 1.0f - 2.0f*rcp_(ex2(xp) + 1.0f); }

// native bf16 convert (hardware cvt, RNE)
__device__ __forceinline__ u16 f2b(float f){
  __bf16 b = (__bf16)f;
  return __builtin_bit_cast(u16, b);
}
__device__ __forceinline__ u32 f2b2(float lo, float hi){
  return (u32)f2b(lo) | ((u32)f2b(hi) << 16);
}

struct __align__(16) SM {
  u16 xh[2][16*XROW];
  u16 hh[2][16*HROW];
};

__device__ __forceinline__ int swx(int e, int k){ return e*XROW + (k ^ ((e&7)<<3)); }
__device__ __forceinline__ int swh(int e, int k){ return e*HROW + (k ^ ((e&7)<<3)); }

__device__ __forceinline__ bf16x8 pack8s(const float* src, float s){
  union { bf16x8 v; u16 h[8]; } fr;
  #pragma unroll
  for (int j = 0; j < 8; ++j) fr.h[j] = f2b(src[j]*s);
  return fr.v;
}

extern "C" __global__ __launch_bounds__(128, 1)
void decoder_kernel(const float* __restrict__ obs,  const float* __restrict__ lat,
                    const float* __restrict__ Wfc,  const float* __restrict__ bfc,
                    const float* __restrict__ Wih0, const float* __restrict__ Whh0,
                    const float* __restrict__ bih0, const float* __restrict__ bhh0,
                    const float* __restrict__ Wih1, const float* __restrict__ Whh1,
                    const float* __restrict__ bih1, const float* __restrict__ bhh1,
                    const float* __restrict__ Wmlp, const float* __restrict__ bmlp,
                    float* __restrict__ out)
{
  __shared__ SM sm;
  const int tid = threadIdx.x;
  const int ebase = blockIdx.x * ET;
  const int mh = tid >> 6;        // wave 0..1 = m-half
  const int l  = tid & 63;
  const int lr = l & 15;          // row/col in 16-tile; e within stream
  const int kq = l >> 4;          // k-quad 0..3

  // ---- one-time LDS init: x = obs[15] (bf16); h_init -> h0/h1 parity 0 ----
  {
    int e = tid >> 2, c0 = (tid & 3)*24;
    int s = e >> 4, er = e & 15;
    const float* src = obs + ((size_t)(15*BATCH) + ebase + e)*96 + c0;
    #pragma unroll
    for (int j = 0; j < 12; ++j){
      float2 v = *(const float2*)(src + 2*j);
      *(u32*)&sm.xh[s][swx(er, c0 + 2*j)] = f2b2(v.x, v.y);
    }
  }
  {
    int u = tid & 31, e8 = (tid >> 5)*8;
    const float* wf = Wfc + u*16;
    float bb = bfc[u];
    #pragma unroll
    for (int r = 0; r < 8; ++r){
      int e = e8 + r, s = e >> 4, er = e & 15;
      const float* lp = lat + (size_t)(ebase + e)*16;
      float a = bb;
      #pragma unroll
      for (int j = 0; j < 16; ++j) a = fmaf(wf[j], lp[j], a);
      u16 hb = f2b(a);
      sm.hh[s][swh(er, 0 + u)]  = hb;   // h0 parity 0 (rows 0..31)
      sm.hh[s][swh(er, 64 + u)] = hb;   // h1 parity 0 (rows 64..95)
    }
  }

  // ---- preload weight A-fragments (step-invariant; gate rows pre-scaled) ----
  bf16x8 aw0[4][4];                 // GEMM0: 4 m-tiles x 4 k-chunks
  #pragma unroll
  for (int i = 0; i < 4; ++i){
    int vg = (mh*4 + i)*16 + lr;
    int g  = (vg & 3)*32 + (vg >> 2);     // gate-permuted row
    float sc = ((vg & 3) == 2) ? LOG2E2 : LOG2E;
    #pragma unroll
    for (int c = 0; c < 4; ++c){
      int k = c*32 + kq*8;
      const float* src = (k < 96) ? (Wih0 + g*96 + k) : (Whh0 + g*32 + (k - 96));
      aw0[i][c] = pack8s(src, sc);
    }
  }
  bf16x8 aw1[4][2];                 // GEMM1: K=64
  #pragma unroll
  for (int i = 0; i < 4; ++i){
    int vg = (mh*4 + i)*16 + lr;
    int g  = (vg & 3)*32 + (vg >> 2);
    float sc = ((vg & 3) == 2) ? LOG2E2 : LOG2E;
    #pragma unroll
    for (int c = 0; c < 2; ++c){
      int k = c*32 + kq*8;
      const float* src = (k < 32) ? (Wih1 + g*32 + k) : (Whh1 + g*32 + (k - 32));
      aw1[i][c] = pack8s(src, sc);
    }
  }
  bf16x8 awm[3];                    // MLP: 3 m-tiles per wave, K=32
  #pragma unroll
  for (int i = 0; i < 3; ++i){
    int o = (mh*3 + i)*16 + lr;
    awm[i] = pack8s(Wmlp + o*32 + kq*8, 1.0f);
  }

  // ---- biases (C-frag rows = kq*4 + r; scaled like their gate rows) ----
  f32x4 bias0v[4], bias1v[4];
  #pragma unroll
  for (int i = 0; i < 4; ++i){
    int u = (mh*4 + i)*4 + kq;
    #pragma unroll
    for (int r = 0; r < 4; ++r){
      int g = r*32 + u;
      float sc = (r == 2) ? LOG2E2 : LOG2E;
      bias0v[i][r] = (bih0[g] + bhh0[g])*sc;
      bias1v[i][r] = (bih1[g] + bhh1[g])*sc;
    }
  }
  f32x4 biasmv[3];
  #pragma unroll
  for (int i = 0; i < 3; ++i){
    int o0 = (mh*3 + i)*16 + kq*4;
    #pragma unroll
    for (int r = 0; r < 4; ++r) biasmv[i][r] = bmlp[o0 + r];
  }

  float c0s[2][4] = {{0,0,0,0},{0,0,0,0}};
  float c1s[2][4] = {{0,0,0,0},{0,0,0,0}};

  __syncthreads();   // init visible (one-time)

  f32x4 am[2][3];    // MLP results, stored to global AFTER B5

  for (int t = 0; t < PRED; ++t){
    const int p = t & 1;
    // ---- P1: GEMM0 both streams; h0(t-1) from hh parity p ----
    f32x4 g0[2][4];
    #pragma unroll
    for (int s = 0; s < 2; ++s){
      bf16x8 bx0 = *(const bf16x8*)&sm.xh[s][swx(lr, 0*32 + kq*8)];
      bf16x8 bx1 = *(const bf16x8*)&sm.xh[s][swx(lr, 1*32 + kq*8)];
      bf16x8 bx2 = *(const bf16x8*)&sm.xh[s][swx(lr, 2*32 + kq*8)];
      bf16x8 bx3 = *(const bf16x8*)&sm.hh[s][swh(lr, 32*p + kq*8)];
      #pragma unroll
      for (int i = 0; i < 4; ++i){
        f32x4 a = bias0v[i];
        a = __builtin_amdgcn_mfma_f32_16x16x32_bf16(aw0[i][0], bx0, a, 0, 0, 0);
        a = __builtin_amdgcn_mfma_f32_16x16x32_bf16(aw0[i][1], bx1, a, 0, 0, 0);
        a = __builtin_amdgcn_mfma_f32_16x16x32_bf16(aw0[i][2], bx2, a, 0, 0, 0);
        a = __builtin_amdgcn_mfma_f32_16x16x32_bf16(aw0[i][3], bx3, a, 0, 0, 0);
        g0[s][i] = a;
      }
    }
    // ---- LSTM0 activation; h0(t) -> hh parity p^1 (single write) ----
    #pragma unroll
    for (int s = 0; s < 2; ++s)
      #pragma unroll
      for (int i = 0; i < 4; ++i){
        float ig = sigm2(g0[s][i][0]);
        float fg = sigm2(g0[s][i][1]);
        float gg = tanh2(g0[s][i][2]);
        float og = sigm2(g0[s][i][3]);
        float cn = fmaf(fg, c0s[s][i], ig*gg);
        c0s[s][i] = cn;
        int u = (mh*4 + i)*4 + kq;
        sm.hh[s][swh(lr, 32*(p^1) + u)] = f2b(og * tanh2(cn*LOG2E2));
      }
    BARRIER_NOVM();   // B2: h0(t) visible
    // ---- P3: GEMM1 both streams; h0(t) from p^1, h1(t-1) from 64+32p ----
    f32x4 g1[2][4];
    #pragma unroll
    for (int s = 0; s < 2; ++s){
      bf16x8 bh0 = *(const bf16x8*)&sm.hh[s][swh(lr, 32*(p^1) + kq*8)];
      bf16x8 bh1 = *(const bf16x8*)&sm.hh[s][swh(lr, 64 + 32*p + kq*8)];
      #pragma unroll
      for (int i = 0; i < 4; ++i){
        f32x4 a = bias1v[i];
        a = __builtin_amdgcn_mfma_f32_16x16x32_bf16(aw1[i][0], bh0, a, 0, 0, 0);
        a = __builtin_amdgcn_mfma_f32_16x16x32_bf16(aw1[i][1], bh1, a, 0, 0, 0);
        g1[s][i] = a;
      }
    }
    #pragma unroll
    for (int s = 0; s < 2; ++s)
      #pragma unroll
      for (int i = 0; i < 4; ++i){
        float ig = sigm2(g1[s][i][0]);
        float fg = sigm2(g1[s][i][1]);
        float gg = tanh2(g1[s][i][2]);
        float og = sigm2(g1[s][i][3]);
        float cn = fmaf(fg, c1s[s][i], ig*gg);
        c1s[s][i] = cn;
        int u = (mh*4 + i)*4 + kq;
        sm.hh[s][swh(lr, 64 + 32*(p^1) + u)] = f2b(og * tanh2(cn*LOG2E2));
      }
    BARRIER_NOVM();   // B4: h1(t) visible
    // ---- P4: MLP both streams (bf16 h1 only); feedback next x to xh ----
    #pragma unroll
    for (int s = 0; s < 2; ++s){
      bf16x8 bmh = *(const bf16x8*)&sm.hh[s][swh(lr, 64 + 32*(p^1) + kq*8)];
      #pragma unroll
      for (int i = 0; i < 3; ++i){
        f32x4 a = biasmv[i];
        a = __builtin_amdgcn_mfma_f32_16x16x32_bf16(awm[i], bmh, a, 0, 0, 0);
        am[s][i] = a;
        int o0 = (mh*3 + i)*16 + kq*4;
        *(u32*)&sm.xh[s][swx(lr, o0)]     = f2b2(a[0], a[1]);   // next step's x
        *(u32*)&sm.xh[s][swx(lr, o0 + 2)] = f2b2(a[2], a[3]);
      }
    }
    BARRIER_NOVM();   // B5: next x visible for P1(t+1)
    // ---- global stores AFTER barrier: never drained in-loop ----
    #pragma unroll
    for (int s = 0; s < 2; ++s){
      float* outb = out + (size_t)t*BATCH*96 + (size_t)(ebase + s*16 + lr)*96;
      #pragma unroll
      for (int i = 0; i < 3; ++i){
        int o0 = (mh*3 + i)*16 + kq*4;
        *(f32x4*)(outb + o0) = am[s][i];
      }
    }
  }
}

extern "C" void kernel_launch(void* const* d_in, const int* in_sizes, int n_in,
                              void* d_out, int out_size, void* d_ws, size_t ws_size,
                              hipStream_t stream){
  decoder_kernel<<<dim3(BATCH/ET), dim3(128), 0, stream>>>(
      (const float*)d_in[0],  (const float*)d_in[1],
      (const float*)d_in[3],  (const float*)d_in[4],
      (const float*)d_in[5],  (const float*)d_in[6],
      (const float*)d_in[7],  (const float*)d_in[8],
      (const float*)d_in[9],  (const float*)d_in[10],
      (const float*)d_in[11], (const float*)d_in[12],
      (const float*)d_in[13], (const float*)d_in[14],
      (float*)d_out);
}